// Round 3
// baseline (503.094 us; speedup 1.0000x reference)
//
#include <hip/hip_runtime.h>
#include <cstdint>

typedef unsigned long long u64;

constexpr int B = 4096;
constexpr int D = 8192;
constexpr int H = 4096;
constexpr int L = 128;
constexpr int DW = D / 64;   // 128 u64 words along d
constexpr int HW = H / 64;   // 64 u64 words along h

// ================= Kernel A: pack x, pack wb, cmin, clf row-sums ===========
// Blocks [0,B):       pack x row r -> xp[r][DW]            (row-major)
// Blocks [B,B+H):     pack (ew>0.5) row h -> wbpw[w][H]    (word-major)
// Blocks [B+H,+16):   cmin for 256 h each
// Blocks [B+H+16,+128): clf row-sum per l
__global__ __launch_bounds__(256) void k_A(const float* __restrict__ x,
                                           const float* __restrict__ e,
                                           const float* __restrict__ bias0,
                                           const float* __restrict__ clf,
                                           u64* __restrict__ xp,
                                           u64* __restrict__ wbpw,
                                           int* __restrict__ cmin,
                                           float* __restrict__ R) {
    __shared__ float s[256];
    int r = blockIdx.x;
    int lane = threadIdx.x & 63;
    int wave = threadIdx.x >> 6;

    if (r < B + H) {
        bool is_x = (r < B);
        const float* row = is_x ? (x + (size_t)r * D) : (e + (size_t)(r - B) * D);
        #pragma unroll 1
        for (int it = 0; it < 8; ++it) {
            int chunk = wave * 8 + it;            // [0,32): 256-element chunk
            int base = chunk * 256;
            u64 m[4];
            #pragma unroll
            for (int k = 0; k < 4; ++k) {
                float v = row[base + k * 64 + lane];   // coalesced 256B per k
                m[k] = __ballot(v > 0.5f);
            }
            if (lane == 0) {
                if (is_x) {
                    u64* orow = xp + (size_t)r * DW + chunk * 4;
                    orow[0] = m[0]; orow[1] = m[1]; orow[2] = m[2]; orow[3] = m[3];
                } else {
                    int h = r - B;
                    #pragma unroll
                    for (int k = 0; k < 4; ++k)
                        wbpw[(size_t)(chunk * 4 + k) * H + h] = m[k];
                }
            }
        }
    } else if (r < B + H + 16) {
        // minimal integer c with (float)c + bias0[h] > 1.0f (exact fp32 semantics)
        int h = (r - B - H) * 256 + threadIdx.x;
        float b0 = bias0[h];
        int c = (int)(1.0f - b0);
        if (c < 0) c = 0;
        int guard = 0;
        while ((float)c + b0 <= 1.0f && guard++ < 100000) ++c;
        while (c > 0 && (float)(c - 1) + b0 > 1.0f) --c;
        cmin[h] = c;
    } else {
        // clf row-sum for l = r - (B+H+16)
        int l = r - (B + H + 16);
        float acc = 0.f;
        for (int h = threadIdx.x; h < H; h += 256) acc += clf[(size_t)l * H + h];
        s[threadIdx.x] = acc;
        __syncthreads();
        for (int off = 128; off > 0; off >>= 1) {
            if ((int)threadIdx.x < off) s[threadIdx.x] += s[threadIdx.x + off];
            __syncthreads();
        }
        if (threadIdx.x == 0) R[l] = s[0];
    }
}

// ================= Kernel TB: bit-transpose + base row =====================
// Blocks [0,2048): wbpw -> wbtp[d][HW] (bit j of word wh = wb[wh*64+j][d])
// Blocks [2048,+128): basef[d] = ((colsum wb[:,d]) + bias3[d] > 1) ? 1 : 0,
//                     computed directly from wbpw (no dependency on wbtp).
__global__ __launch_bounds__(256) void k_TB(const u64* __restrict__ wbpw,
                                            const float* __restrict__ bias3,
                                            u64* __restrict__ wbtp,
                                            float* __restrict__ basef) {
    int r = blockIdx.x;
    int lane = threadIdx.x & 63;
    int wave = threadIdx.x >> 6;
    if (r < 2048) {
        int wid = r * 4 + wave;     // [0, DW*HW)
        int dblock = wid >> 6;      // [0, DW)
        int wh = wid & (HW - 1);    // [0, HW)
        u64 Wj = wbpw[(size_t)dblock * H + wh * 64 + lane];
        u64 myword = 0;
        #pragma unroll 1
        for (int jj = 0; jj < 64; ++jj) {
            u64 m = __ballot((int)((Wj >> jj) & 1ull));
            if (lane == jj) myword = m;
        }
        wbtp[(size_t)(dblock * 64 + lane) * HW + wh] = myword;
    } else {
        int w = r - 2048;           // d-word index [0, DW)
        __shared__ int sc[4][64];
        int cnt = 0;
        #pragma unroll 1
        for (int g = wave; g < 64; g += 4) {
            u64 W = wbpw[(size_t)w * H + g * 64 + lane];   // coalesced 512B
            #pragma unroll 1
            for (int jj = 0; jj < 64; ++jj) {
                u64 m = __ballot((int)((W >> jj) & 1ull)); // mask over h-group
                if (lane == jj) cnt += (int)__popcll(m);
            }
        }
        sc[wave][lane] = cnt;
        __syncthreads();
        if (wave == 0) {
            int tot = sc[0][lane] + sc[1][lane] + sc[2][lane] + sc[3][lane];
            int d = w * 64 + lane;
            basef[d] = ((float)tot + bias3[d] > 1.0f) ? 1.0f : 0.0f;
        }
    }
}

// ================= Kernel Z: z scan + all outputs, one block per b row =====
__global__ __launch_bounds__(256) void k_Z(const u64* __restrict__ xp,
                                           const u64* __restrict__ wbpw,
                                           const u64* __restrict__ wbtp,
                                           const int* __restrict__ cmin,
                                           const float* __restrict__ basef,
                                           const float* __restrict__ R,
                                           const float* __restrict__ clf,
                                           const float* __restrict__ bias3,
                                           float* __restrict__ out0,
                                           float* __restrict__ out1,
                                           float* __restrict__ zout) {
    __shared__ u64 zrow[HW];
    __shared__ int s_nz;
    int b = blockIdx.x;
    int lane = threadIdx.x & 63;
    int wave = threadIdx.x >> 6;
    const u64* __restrict__ xr = xp + (size_t)b * DW;

    // ---- phase 1: z row via early-exit popcount scan ----
    #pragma unroll 1
    for (int i = 0; i < HW / 4; ++i) {
        int hb = wave * (HW / 4) + i;
        int h = hb * 64 + lane;
        int cm = cmin[h];
        int cnt = 0;
        #pragma unroll 1
        for (int w = 0; w < DW; ++w) {
            if (__all(cnt >= cm)) break;       // typ. 3-4 iterations
            if (cnt < cm) {
                u64 a = xr[w];                         // wave-uniform
                u64 wv = wbpw[(size_t)w * H + h];      // coalesced 512B
                cnt += (int)__popcll(a & wv);
            }
        }
        int zb = (cnt >= cm) ? 1 : 0;
        zout[(size_t)b * H + h] = zb ? 1.0f : 0.0f;    // coalesced 256B
        u64 m = __ballot(zb);
        if (lane == 0) zrow[hb] = m;
    }
    __syncthreads();

    // ---- phase 2: nz via wave-0 reduce ----
    if (wave == 0) {
        int c = (int)__popcll(zrow[lane]);
        #pragma unroll
        for (int off = 32; off > 0; off >>= 1) c += __shfl_down(c, off);
        if (lane == 0) s_nz = H - c;
    }
    __syncthreads();
    int nz = s_nz;

    // ---- phase 3: outputs ----
    if (nz == 0) {
        if (threadIdx.x < L) out1[(size_t)b * L + threadIdx.x] = R[threadIdx.x];
        float4* o4 = (float4*)(out0 + (size_t)b * D);
        const float4* b4 = (const float4*)basef;
        #pragma unroll
        for (int t = threadIdx.x; t < D / 4; t += 256) o4[t] = b4[t];
    } else {
        if (threadIdx.x < L) {
            int l = threadIdx.x;
            float acc = 0.f;
            for (int wh = 0; wh < HW; ++wh) {
                u64 m = zrow[wh];
                while (m) {
                    int j = __ffsll(m) - 1;
                    acc += clf[(size_t)l * H + wh * 64 + j];
                    m &= m - 1;
                }
            }
            out1[(size_t)b * L + l] = acc;
        }
        for (int d = threadIdx.x; d < D; d += 256) {
            int ssum = 0;
            for (int w = 0; w < HW; ++w)
                ssum += (int)__popcll(zrow[w] & wbtp[(size_t)d * HW + w]);
            out0[(size_t)b * D + d] = ((float)ssum + bias3[d] > 1.0f) ? 1.0f : 0.0f;
        }
    }
}

// ================= launch ==================================================

extern "C" void kernel_launch(void* const* d_in, const int* in_sizes, int n_in,
                              void* d_out, int out_size, void* d_ws, size_t ws_size,
                              hipStream_t stream) {
    const float* x   = (const float*)d_in[0];
    const float* ew  = (const float*)d_in[1];
    const float* b0  = (const float*)d_in[2];
    const float* b3  = (const float*)d_in[3];
    const float* clf = (const float*)d_in[4];

    float* out0 = (float*)d_out;                 // [B][D]
    float* out1 = out0 + (size_t)B * D;          // [B][L]
    float* zout = out1 + (size_t)B * L;          // [B][H]

    char* ws = (char*)d_ws;
    u64* xp     = (u64*)(ws);                        // 4 MB
    u64* wbpw   = (u64*)(ws + (4ull << 20));         // 4 MB
    u64* wbtp   = (u64*)(ws + (8ull << 20));         // 4 MB
    float* basef = (float*)(ws + (12ull << 20));     // 32 KB
    float* R     = (float*)(ws + (12ull << 20) + 32768);          // 512 B
    int* cmin    = (int*)(ws + (12ull << 20) + 32768 + 512);      // 16 KB

    k_A<<<B + H + 16 + L, 256, 0, stream>>>(x, ew, b0, clf, xp, wbpw, cmin, R);
    k_TB<<<2048 + DW, 256, 0, stream>>>(wbpw, b3, wbtp, basef);
    k_Z<<<B, 256, 0, stream>>>(xp, wbpw, wbtp, cmin, basef, R, clf, b3,
                               out0, out1, zout);
}

// Round 4
// 467.954 us; speedup vs baseline: 1.0751x; 1.0751x over previous
//
#include <hip/hip_runtime.h>
#include <cstdint>

typedef unsigned long long u64;

constexpr int B = 4096;
constexpr int D = 8192;
constexpr int H = 4096;
constexpr int L = 128;
constexpr int DW = D / 64;   // 128 u64 words along d
constexpr int HW = H / 64;   // 64 u64 words along h

// ================= Kernel A: pack x, pack wb, cmin, clf row-sums ===========
// Blocks [0,B):        pack x row r -> xp[r][DW]            (row-major)
// Blocks [B,B+H):      pack (ew>0.5) row h -> wbpw[w][H]    (word-major)
// Blocks [B+H,+16):    cmin for 256 h each
// Blocks [B+H+16,+128): clf row-sum per l
__global__ __launch_bounds__(256) void k_A(const float* __restrict__ x,
                                           const float* __restrict__ e,
                                           const float* __restrict__ bias0,
                                           const float* __restrict__ clf,
                                           u64* __restrict__ xp,
                                           u64* __restrict__ wbpw,
                                           int* __restrict__ cmin,
                                           float* __restrict__ R) {
    __shared__ float s[256];
    int r = blockIdx.x;
    int lane = threadIdx.x & 63;
    int wave = threadIdx.x >> 6;

    if (r < B + H) {
        bool is_x = (r < B);
        const float* row = is_x ? (x + (size_t)r * D) : (e + (size_t)(r - B) * D);
        // Full unroll: 32 independent 256B loads in flight per wave -> BW-bound.
        #pragma unroll
        for (int it = 0; it < 8; ++it) {
            int chunk = wave * 8 + it;            // [0,32): 256-element chunk
            int base = chunk * 256;
            u64 m[4];
            #pragma unroll
            for (int k = 0; k < 4; ++k) {
                float v = row[base + k * 64 + lane];   // coalesced 256B per k
                m[k] = __ballot(v > 0.5f);
            }
            if (lane == 0) {
                if (is_x) {
                    u64* orow = xp + (size_t)r * DW + chunk * 4;
                    orow[0] = m[0]; orow[1] = m[1]; orow[2] = m[2]; orow[3] = m[3];
                } else {
                    int h = r - B;
                    #pragma unroll
                    for (int k = 0; k < 4; ++k)
                        wbpw[(size_t)(chunk * 4 + k) * H + h] = m[k];
                }
            }
        }
    } else if (r < B + H + 16) {
        // minimal integer c with (float)c + bias0[h] > 1.0f (exact fp32 semantics)
        int h = (r - B - H) * 256 + threadIdx.x;
        float b0 = bias0[h];
        int c = (int)(1.0f - b0);
        if (c < 0) c = 0;
        int guard = 0;
        while ((float)c + b0 <= 1.0f && guard++ < 100000) ++c;
        while (c > 0 && (float)(c - 1) + b0 > 1.0f) --c;
        cmin[h] = c;
    } else {
        // clf row-sum for l = r - (B+H+16)
        int l = r - (B + H + 16);
        float acc = 0.f;
        for (int h = threadIdx.x; h < H; h += 256) acc += clf[(size_t)l * H + h];
        s[threadIdx.x] = acc;
        __syncthreads();
        for (int off = 128; off > 0; off >>= 1) {
            if ((int)threadIdx.x < off) s[threadIdx.x] += s[threadIdx.x + off];
            __syncthreads();
        }
        if (threadIdx.x == 0) R[l] = s[0];
    }
}

// ================= Kernel B: base row from column sums of wb ===============
// basef[d] = ((colsum wb[:,d]) + bias3[d] > 1) ? 1 : 0, via ballot colsums.
// 128 blocks (one per d-word).
__global__ __launch_bounds__(256) void k_B(const u64* __restrict__ wbpw,
                                           const float* __restrict__ bias3,
                                           float* __restrict__ basef) {
    int w = blockIdx.x;           // d-word index [0, DW)
    int lane = threadIdx.x & 63;
    int wave = threadIdx.x >> 6;
    __shared__ int sc[4][64];
    int cnt = 0;
    #pragma unroll 1
    for (int g = wave; g < 64; g += 4) {
        u64 W = wbpw[(size_t)w * H + g * 64 + lane];   // coalesced 512B
        #pragma unroll 1
        for (int jj = 0; jj < 64; ++jj) {
            u64 m = __ballot((int)((W >> jj) & 1ull));
            if (lane == jj) cnt += (int)__popcll(m);
        }
    }
    sc[wave][lane] = cnt;
    __syncthreads();
    if (wave == 0) {
        int tot = sc[0][lane] + sc[1][lane] + sc[2][lane] + sc[3][lane];
        int d = w * 64 + lane;
        basef[d] = ((float)tot + bias3[d] > 1.0f) ? 1.0f : 0.0f;
    }
}

// ================= Kernel Z: z scan + all outputs, one block per b row =====
__global__ __launch_bounds__(256) void k_Z(const u64* __restrict__ xp,
                                           const u64* __restrict__ wbpw,
                                           const int* __restrict__ cmin,
                                           const float* __restrict__ basef,
                                           const float* __restrict__ R,
                                           const float* __restrict__ clf,
                                           const float* __restrict__ bias3,
                                           float* __restrict__ out0,
                                           float* __restrict__ out1,
                                           float* __restrict__ zout) {
    __shared__ u64 sxw[DW];    // this row's x bits, 1 KB
    __shared__ u64 zrow[HW];
    __shared__ int s_nz;
    int b = blockIdx.x;
    int lane = threadIdx.x & 63;
    int wave = threadIdx.x >> 6;

    // ---- stage x row into LDS ----
    if (threadIdx.x < DW) sxw[threadIdx.x] = xp[(size_t)b * DW + threadIdx.x];
    __syncthreads();
    u64 x0 = sxw[0], x1 = sxw[1], x2 = sxw[2], x3 = sxw[3];  // wave-uniform bcast

    // ---- phase 1: z row. Branchless 4-word probe (independent loads), rare tail. ----
    #pragma unroll 1
    for (int i = 0; i < HW / 4; ++i) {
        int hb = wave * (HW / 4) + i;
        int h = hb * 64 + lane;
        int cm = cmin[h];
        const u64* __restrict__ wp = wbpw + hb * 64 + lane;
        u64 w0 = wp[0];
        u64 w1 = wp[(size_t)H];
        u64 w2 = wp[(size_t)2 * H];
        u64 w3 = wp[(size_t)3 * H];
        int cnt = (int)__popcll(x0 & w0) + (int)__popcll(x1 & w1)
                + (int)__popcll(x2 & w2) + (int)__popcll(x3 & w3);
        if (!__all(cnt >= cm)) {            // P ~ 2e-3 per wave
            #pragma unroll 1
            for (int w = 4; w < DW; ++w) {
                if (cnt < cm) cnt += (int)__popcll(sxw[w] & wp[(size_t)w * H]);
                if (__all(cnt >= cm)) break;
            }
        }
        int zb = (cnt >= cm) ? 1 : 0;
        u64 m = __ballot(zb);
        if (lane == 0) zrow[hb] = m;
    }
    __syncthreads();

    // ---- phase 2: nz via wave-0 reduce ----
    if (wave == 0) {
        int c = (int)__popcll(zrow[lane]);
        #pragma unroll
        for (int off = 32; off > 0; off >>= 1) c += __shfl_down(c, off);
        if (lane == 0) s_nz = H - c;
    }
    __syncthreads();
    int nz = s_nz;

    // ---- phase 3a: zout, coalesced float4 from zrow bits ----
    {
        float* zr = zout + (size_t)b * H;
        #pragma unroll
        for (int k = 0; k < 4; ++k) {
            int t = threadIdx.x + k * 256;     // float4 index in [0, H/4)
            u64 wzd = zrow[t >> 4];
            int j0 = (t & 15) * 4;
            float4 f;
            f.x = ((wzd >> (j0 + 0)) & 1ull) ? 1.0f : 0.0f;
            f.y = ((wzd >> (j0 + 1)) & 1ull) ? 1.0f : 0.0f;
            f.z = ((wzd >> (j0 + 2)) & 1ull) ? 1.0f : 0.0f;
            f.w = ((wzd >> (j0 + 3)) & 1ull) ? 1.0f : 0.0f;
            ((float4*)zr)[t] = f;
        }
    }

    // ---- phase 3b: classification + recon output ----
    if (nz == 0) {
        if (threadIdx.x < L) out1[(size_t)b * L + threadIdx.x] = R[threadIdx.x];
        float4* o4 = (float4*)(out0 + (size_t)b * D);
        const float4* b4 = (const float4*)basef;
        #pragma unroll
        for (int k = 0; k < 8; ++k) {
            int t = threadIdx.x + k * 256;     // [0, D/4)
            o4[t] = b4[t];
        }
    } else {
        // ---- exact fallback (astronomically rare; correct, not fast) ----
        if (threadIdx.x < L) {
            int l = threadIdx.x;
            float acc = 0.f;
            for (int wh = 0; wh < HW; ++wh) {
                u64 m = zrow[wh];
                while (m) {
                    int j = __ffsll(m) - 1;
                    acc += clf[(size_t)l * H + wh * 64 + j];
                    m &= m - 1;
                }
            }
            out1[(size_t)b * L + l] = acc;
        }
        // out0 via on-the-fly ballot transpose of wbpw masked by z.
        for (int w = wave; w < DW; w += 4) {     // each wave: one d-word at a time
            int acc = 0;                          // count for d = w*64 + lane
            for (int hb = 0; hb < HW; ++hb) {
                u64 Wj = wbpw[(size_t)w * H + hb * 64 + lane];  // lane = h offset
                u64 zm = zrow[hb];
                u64 masked = ((zm >> lane) & 1ull) ? Wj : 0ull;
                for (int jj = 0; jj < 64; ++jj) {
                    u64 bal = __ballot((int)((masked >> jj) & 1ull));
                    if (lane == jj) acc += (int)__popcll(bal);
                }
            }
            int d = w * 64 + lane;
            out0[(size_t)b * D + d] = ((float)acc + bias3[d] > 1.0f) ? 1.0f : 0.0f;
        }
    }
}

// ================= launch ==================================================

extern "C" void kernel_launch(void* const* d_in, const int* in_sizes, int n_in,
                              void* d_out, int out_size, void* d_ws, size_t ws_size,
                              hipStream_t stream) {
    const float* x   = (const float*)d_in[0];
    const float* ew  = (const float*)d_in[1];
    const float* b0  = (const float*)d_in[2];
    const float* b3  = (const float*)d_in[3];
    const float* clf = (const float*)d_in[4];

    float* out0 = (float*)d_out;                 // [B][D]
    float* out1 = out0 + (size_t)B * D;          // [B][L]
    float* zout = out1 + (size_t)B * L;          // [B][H]

    char* ws = (char*)d_ws;
    u64* xp      = (u64*)(ws);                       // 4 MB
    u64* wbpw    = (u64*)(ws + (4ull << 20));        // 4 MB
    float* basef = (float*)(ws + (8ull << 20));      // 32 KB
    float* R     = (float*)(ws + (8ull << 20) + 32768);        // 512 B
    int* cmin    = (int*)(ws + (8ull << 20) + 32768 + 512);    // 16 KB

    k_A<<<B + H + 16 + L, 256, 0, stream>>>(x, ew, b0, clf, xp, wbpw, cmin, R);
    k_B<<<DW, 256, 0, stream>>>(wbpw, b3, basef);
    k_Z<<<B, 256, 0, stream>>>(xp, wbpw, cmin, basef, R, clf, b3,
                               out0, out1, zout);
}

// Round 5
// 456.617 us; speedup vs baseline: 1.1018x; 1.0248x over previous
//
#include <hip/hip_runtime.h>
#include <cstdint>

typedef unsigned long long u64;

constexpr int B = 4096;
constexpr int D = 8192;
constexpr int H = 4096;
constexpr int L = 128;
constexpr int DW = D / 64;   // 128 u64 words along d
constexpr int HW = H / 64;   // 64 u64 words along h

// ================= Kernel P: pack enc_weight rows ==========================
// Grid = H. Block h packs (ew[h][:] > 0.5) -> wbpw[w][H] (word-major).
// Per-lane byte pack: thread t reads 2 contiguous float4 (8 floats -> 1 byte),
// bytes staged in LDS, re-read as u64 words. Loads are dwordx4, 1KB/instr.
__global__ __launch_bounds__(256) void k_P(const float* __restrict__ e,
                                           u64* __restrict__ wbpw) {
    __shared__ u64 sw[DW];                       // 1 KB
    unsigned char* sb = (unsigned char*)sw;
    int h = blockIdx.x;
    const float4* row4 = (const float4*)(e + (size_t)h * D);
    #pragma unroll
    for (int j = 0; j < 4; ++j) {
        int t = j * 256 + threadIdx.x;           // byte index [0, 1024)
        float4 a = row4[2 * t];
        float4 c = row4[2 * t + 1];
        unsigned v = (a.x > 0.5f ? 1u : 0u) | (a.y > 0.5f ? 2u : 0u)
                   | (a.z > 0.5f ? 4u : 0u) | (a.w > 0.5f ? 8u : 0u)
                   | (c.x > 0.5f ? 16u : 0u) | (c.y > 0.5f ? 32u : 0u)
                   | (c.z > 0.5f ? 64u : 0u) | (c.w > 0.5f ? 128u : 0u);
        sb[t] = (unsigned char)v;                // byte t = elements 8t..8t+7
    }
    __syncthreads();
    if (threadIdx.x < DW)
        wbpw[(size_t)threadIdx.x * H + h] = sw[threadIdx.x];
}

// ================= Kernel B: basef + cmin + clf row-sums ===================
// Blocks [0,128):    basef for d-word w via ballot colsums of wbpw
// Blocks [128,144):  cmin for 256 h each
// Blocks [144,272):  clf row-sum per l
__global__ __launch_bounds__(256) void k_B(const u64* __restrict__ wbpw,
                                           const float* __restrict__ bias0,
                                           const float* __restrict__ bias3,
                                           const float* __restrict__ clf,
                                           float* __restrict__ basef,
                                           int* __restrict__ cmin,
                                           float* __restrict__ R) {
    __shared__ int sc[4][64];
    __shared__ float s[256];
    int r = blockIdx.x;
    int lane = threadIdx.x & 63;
    int wave = threadIdx.x >> 6;
    if (r < DW) {
        int w = r;
        int cnt = 0;
        #pragma unroll 1
        for (int g = wave; g < 64; g += 4) {
            u64 W = wbpw[(size_t)w * H + g * 64 + lane];   // coalesced 512B
            #pragma unroll 1
            for (int jj = 0; jj < 64; ++jj) {
                u64 m = __ballot((int)((W >> jj) & 1ull));
                if (lane == jj) cnt += (int)__popcll(m);
            }
        }
        sc[wave][lane] = cnt;
        __syncthreads();
        if (wave == 0) {
            int tot = sc[0][lane] + sc[1][lane] + sc[2][lane] + sc[3][lane];
            int d = w * 64 + lane;
            basef[d] = ((float)tot + bias3[d] > 1.0f) ? 1.0f : 0.0f;
        }
    } else if (r < DW + 16) {
        // minimal integer c with (float)c + bias0[h] > 1.0f (exact fp32)
        int h = (r - DW) * 256 + threadIdx.x;
        float b0 = bias0[h];
        int c = (int)(1.0f - b0);
        if (c < 0) c = 0;
        int guard = 0;
        while ((float)c + b0 <= 1.0f && guard++ < 100000) ++c;
        while (c > 0 && (float)(c - 1) + b0 > 1.0f) --c;
        cmin[h] = c;
    } else {
        int l = r - (DW + 16);
        float acc = 0.f;
        for (int hh = threadIdx.x; hh < H; hh += 256) acc += clf[(size_t)l * H + hh];
        s[threadIdx.x] = acc;
        __syncthreads();
        for (int off = 128; off > 0; off >>= 1) {
            if ((int)threadIdx.x < off) s[threadIdx.x] += s[threadIdx.x + off];
            __syncthreads();
        }
        if (threadIdx.x == 0) R[l] = s[0];
    }
}

// ================= Kernel Z: pack x row + z scan + all outputs =============
// One block per b row. x is read directly (float4) and packed in-block.
__global__ __launch_bounds__(256) void k_Z(const float* __restrict__ x,
                                           const u64* __restrict__ wbpw,
                                           const int* __restrict__ cmin,
                                           const float* __restrict__ basef,
                                           const float* __restrict__ R,
                                           const float* __restrict__ clf,
                                           const float* __restrict__ bias3,
                                           float* __restrict__ out0,
                                           float* __restrict__ out1,
                                           float* __restrict__ zout) {
    __shared__ u64 sxw[DW];    // this row's x bits, 1 KB
    __shared__ u64 zrow[HW];
    __shared__ int s_nz;
    unsigned char* sxb = (unsigned char*)sxw;
    int b = blockIdx.x;
    int lane = threadIdx.x & 63;
    int wave = threadIdx.x >> 6;

    // ---- phase 0: pack x row into LDS (dwordx4 loads, byte pack) ----
    const float4* xr4 = (const float4*)(x + (size_t)b * D);
    #pragma unroll
    for (int j = 0; j < 4; ++j) {
        int t = j * 256 + threadIdx.x;
        float4 a = xr4[2 * t];
        float4 c = xr4[2 * t + 1];
        unsigned v = (a.x > 0.5f ? 1u : 0u) | (a.y > 0.5f ? 2u : 0u)
                   | (a.z > 0.5f ? 4u : 0u) | (a.w > 0.5f ? 8u : 0u)
                   | (c.x > 0.5f ? 16u : 0u) | (c.y > 0.5f ? 32u : 0u)
                   | (c.z > 0.5f ? 64u : 0u) | (c.w > 0.5f ? 128u : 0u);
        sxb[t] = (unsigned char)v;
    }
    __syncthreads();
    u64 x0 = sxw[0], x1 = sxw[1], x2 = sxw[2], x3 = sxw[3];  // broadcast reads

    // ---- phase 1: z row. Branchless 4-word probe, rare tail. ----
    #pragma unroll 1
    for (int i = 0; i < HW / 4; ++i) {
        int hb = wave * (HW / 4) + i;
        int h = hb * 64 + lane;
        int cm = cmin[h];
        const u64* __restrict__ wp = wbpw + hb * 64 + lane;
        u64 w0 = wp[0];
        u64 w1 = wp[(size_t)H];
        u64 w2 = wp[(size_t)2 * H];
        u64 w3 = wp[(size_t)3 * H];
        int cnt = (int)__popcll(x0 & w0) + (int)__popcll(x1 & w1)
                + (int)__popcll(x2 & w2) + (int)__popcll(x3 & w3);
        if (!__all(cnt >= cm)) {            // P ~ 2e-3 per wave
            #pragma unroll 1
            for (int w = 4; w < DW; ++w) {
                if (cnt < cm) cnt += (int)__popcll(sxw[w] & wp[(size_t)w * H]);
                if (__all(cnt >= cm)) break;
            }
        }
        int zb = (cnt >= cm) ? 1 : 0;
        u64 m = __ballot(zb);
        if (lane == 0) zrow[hb] = m;
    }
    __syncthreads();

    // ---- phase 2: nz via wave-0 reduce ----
    if (wave == 0) {
        int c = (int)__popcll(zrow[lane]);
        #pragma unroll
        for (int off = 32; off > 0; off >>= 1) c += __shfl_down(c, off);
        if (lane == 0) s_nz = H - c;
    }
    __syncthreads();
    int nz = s_nz;

    // ---- phase 3a: zout, coalesced float4 from zrow bits ----
    {
        float* zr = zout + (size_t)b * H;
        #pragma unroll
        for (int k = 0; k < 4; ++k) {
            int t = threadIdx.x + k * 256;     // float4 index in [0, H/4)
            u64 wzd = zrow[t >> 4];
            int j0 = (t & 15) * 4;
            float4 f;
            f.x = ((wzd >> (j0 + 0)) & 1ull) ? 1.0f : 0.0f;
            f.y = ((wzd >> (j0 + 1)) & 1ull) ? 1.0f : 0.0f;
            f.z = ((wzd >> (j0 + 2)) & 1ull) ? 1.0f : 0.0f;
            f.w = ((wzd >> (j0 + 3)) & 1ull) ? 1.0f : 0.0f;
            ((float4*)zr)[t] = f;
        }
    }

    // ---- phase 3b: classification + recon output ----
    if (nz == 0) {
        if (threadIdx.x < L) out1[(size_t)b * L + threadIdx.x] = R[threadIdx.x];
        float4* o4 = (float4*)(out0 + (size_t)b * D);
        const float4* b4 = (const float4*)basef;
        #pragma unroll
        for (int k = 0; k < 8; ++k) {
            int t = threadIdx.x + k * 256;     // [0, D/4)
            o4[t] = b4[t];
        }
    } else {
        // ---- exact fallback (astronomically rare; correct, not fast) ----
        if (threadIdx.x < L) {
            int l = threadIdx.x;
            float acc = 0.f;
            for (int wh = 0; wh < HW; ++wh) {
                u64 m = zrow[wh];
                while (m) {
                    int j = __ffsll(m) - 1;
                    acc += clf[(size_t)l * H + wh * 64 + j];
                    m &= m - 1;
                }
            }
            out1[(size_t)b * L + l] = acc;
        }
        // out0 via on-the-fly ballot transpose of wbpw masked by z.
        for (int w = wave; w < DW; w += 4) {
            int acc = 0;                          // count for d = w*64 + lane
            for (int hb = 0; hb < HW; ++hb) {
                u64 Wj = wbpw[(size_t)w * H + hb * 64 + lane];
                u64 zm = zrow[hb];
                u64 masked = ((zm >> lane) & 1ull) ? Wj : 0ull;
                for (int jj = 0; jj < 64; ++jj) {
                    u64 bal = __ballot((int)((masked >> jj) & 1ull));
                    if (lane == jj) acc += (int)__popcll(bal);
                }
            }
            int d = w * 64 + lane;
            out0[(size_t)b * D + d] = ((float)acc + bias3[d] > 1.0f) ? 1.0f : 0.0f;
        }
    }
}

// ================= launch ==================================================

extern "C" void kernel_launch(void* const* d_in, const int* in_sizes, int n_in,
                              void* d_out, int out_size, void* d_ws, size_t ws_size,
                              hipStream_t stream) {
    const float* x   = (const float*)d_in[0];
    const float* ew  = (const float*)d_in[1];
    const float* b0  = (const float*)d_in[2];
    const float* b3  = (const float*)d_in[3];
    const float* clf = (const float*)d_in[4];

    float* out0 = (float*)d_out;                 // [B][D]
    float* out1 = out0 + (size_t)B * D;          // [B][L]
    float* zout = out1 + (size_t)B * L;          // [B][H]

    char* ws = (char*)d_ws;
    u64* wbpw    = (u64*)(ws);                       // 4 MB
    float* basef = (float*)(ws + (4ull << 20));      // 32 KB
    float* R     = (float*)(ws + (4ull << 20) + 32768);        // 512 B
    int* cmin    = (int*)(ws + (4ull << 20) + 32768 + 512);    // 16 KB

    k_P<<<H, 256, 0, stream>>>(ew, wbpw);
    k_B<<<DW + 16 + L, 256, 0, stream>>>(wbpw, b0, b3, clf, basef, cmin, R);
    k_Z<<<B, 256, 0, stream>>>(x, wbpw, cmin, basef, R, clf, b3,
                               out0, out1, zout);
}